// Round 17
// baseline (70.275 us; speedup 1.0000x reference)
//
#include <hip/hip_runtime.h>
#include <hip/hip_bf16.h>

#define T_ 64
#define S_ 64
#define B_ 128
#define E_ 64
#define H_ 4

typedef float f32x4 __attribute__((ext_vector_type(4)));
typedef short bf16x8 __attribute__((ext_vector_type(8)));

static __device__ __forceinline__ short f2b(float f) {
    union { __hip_bfloat16 h; short s; } u;
    u.h = __float2bfloat16(f);
    return u.s;
}

// ---------------------------------------------------------------------------
// K1: qkv projection. qkv layout: [3][T][B][E].
// Block 256 preps relW bf16 fragment-linear (frags 0..15) + 4 shifted-identity
// frags (16..19) into wBf. seg==0 emits qpb[i] = (q + rel_bias_a) bf16
// A-fragment pages; seg==1 emits kpb[j] = (k + rel_bias_b) pages. Both sides
// of the logit product are then pure MFMA in k_logits (no scalar q/k loads).
// ---------------------------------------------------------------------------
__global__ __launch_bounds__(256) void k_qkv(
    const float* __restrict__ qin, const float* __restrict__ kin,
    const float* __restrict__ vin, const float* __restrict__ W,
    const float* __restrict__ bias, float* __restrict__ qkv,
    const float* __restrict__ relW, const float* __restrict__ relBias,
    ushort* __restrict__ wBf, unsigned int* __restrict__ kpbW,
    unsigned int* __restrict__ qpbW)
{
    const int tid = threadIdx.x;

    if (blockIdx.x == 256) {
        #pragma unroll
        for (int li = 0; li < 8; ++li) {
            int f4 = li * 256 + tid;             // 0..2047 = o*16 + e4
            int o = f4 >> 4, e4 = f4 & 15;
            float4 wv = reinterpret_cast<const float4*>(relW)[f4];
            ushort4 bv;
            bv.x = (ushort)f2b(wv.x); bv.y = (ushort)f2b(wv.y);
            bv.z = (ushort)f2b(wv.z); bv.w = (ushort)f2b(wv.w);
            int ot = o >> 4, cc = o & 15;
            int ks = e4 >> 3, rqb = (e4 & 7) >> 1, half = e4 & 1;
            int dest = (ot * 2 + ks) * 512 + (rqb * 16 + cc) * 8 + half * 4;
            *reinterpret_cast<ushort4*>(wBf + dest) = bv;
        }
        #pragma unroll
        for (int li = 0; li < 8; ++li) {
            int t = li * 256 + tid;              // 0..2047
            int ot = t >> 9, lane = (t >> 3) & 63, e = t & 7;
            int cI = lane & 15, rqI = lane >> 4;
            wBf[8192 + t] =
                (rqI * 8 + e == (ot & 1) * 16 + cI) ? (ushort)0x3F80 : (ushort)0;
        }
        return;
    }

    __shared__ float xs[3][32 * 68];
    __shared__ float WTs[64 * 68];
    const int row0 = blockIdx.x * 32;

    #pragma unroll
    for (int l = 0; l < 6; ++l) {
        int f4 = l * 256 + tid;
        int src = f4 >> 9, rem = f4 & 511;
        int r = rem >> 4, e0 = (rem & 15) << 2;
        const float* xin = (src == 0) ? qin : (src == 1 ? kin : vin);
        float4 xv = reinterpret_cast<const float4*>(xin)[(size_t)(row0 + r) * 16 + (e0 >> 2)];
        float* dst = &xs[src][r * 68];
        dst[e0] = xv.x; dst[e0 + 1] = xv.y; dst[e0 + 2] = xv.z; dst[e0 + 3] = xv.w;
    }

    const int rq = tid >> 5, og = tid & 31;
    const int r0 = rq * 4, op0 = og * 2;

    for (int seg = 0; seg < 3; ++seg) {
        __syncthreads();
        #pragma unroll
        for (int l = 0; l < 4; ++l) {
            int f4 = l * 256 + tid;
            int o = f4 >> 4, e0 = (f4 & 15) << 2;
            float4 wv = reinterpret_cast<const float4*>(W)[(size_t)(seg * 64 + o) * 16 + (e0 >> 2)];
            WTs[(e0 + 0) * 68 + o] = wv.x; WTs[(e0 + 1) * 68 + o] = wv.y;
            WTs[(e0 + 2) * 68 + o] = wv.z; WTs[(e0 + 3) * 68 + o] = wv.w;
        }
        __syncthreads();

        float acc[4][2];
        #pragma unroll
        for (int rr = 0; rr < 4; ++rr) {
            acc[rr][0] = bias[seg * 64 + op0];
            acc[rr][1] = bias[seg * 64 + op0 + 1];
        }
        const float* xsrc = xs[seg];
        #pragma unroll 4
        for (int e = 0; e < 64; ++e) {
            float w0 = WTs[e * 68 + op0];
            float w1 = WTs[e * 68 + op0 + 1];
            #pragma unroll
            for (int rr = 0; rr < 4; ++rr) {
                float xv = xsrc[(r0 + rr) * 68 + e];
                acc[rr][0] += xv * w0;
                acc[rr][1] += xv * w1;
            }
        }
        #pragma unroll
        for (int rr = 0; rr < 4; ++rr) {
            float2 ov = make_float2(acc[rr][0], acc[rr][1]);
            reinterpret_cast<float2*>(
                &qkv[((size_t)seg * T_ * B_ + row0 + r0 + rr) * E_ + op0])[0] = ov;
        }
        if (seg == 0) {
            // qpb page: (q + bias_a) as bf16 A-frag pages, mirror of kpb
            #pragma unroll
            for (int rr = 0; rr < 4; ++rr) {
                int row = row0 + r0 + rr;         // = i*128 + b
                int ii = row >> 7, b = row & 127;
                float qb0 = acc[rr][0] + relBias[op0];
                float qb1 = acc[rr][1] + relBias[op0 + 1];
                unsigned int u = (unsigned int)(ushort)f2b(qb0) |
                                 ((unsigned int)(ushort)f2b(qb1) << 16);
                int off = ii * 8192 + (op0 >> 5) * 4096 + (b >> 4) * 512 +
                          ((b & 15) + ((op0 & 31) >> 3) * 16) * 8 + (op0 & 7);
                qpbW[off >> 1] = u;
            }
        }
        if (seg == 1) {
            #pragma unroll
            for (int rr = 0; rr < 4; ++rr) {
                int row = row0 + r0 + rr;         // = j*128 + b
                int jj = row >> 7, b = row & 127;
                float kb0 = acc[rr][0] + relBias[64 + op0];
                float kb1 = acc[rr][1] + relBias[64 + op0 + 1];
                unsigned int u = (unsigned int)(ushort)f2b(kb0) |
                                 ((unsigned int)(ushort)f2b(kb1) << 16);
                int off = jj * 8192 + (op0 >> 5) * 4096 + (b >> 4) * 512 +
                          ((b & 15) + ((op0 & 31) >> 3) * 16) * 8 + (op0 & 7);
                kpbW[off >> 1] = u;
            }
        }
    }
}

// ---------------------------------------------------------------------------
// K2a: fused relation-projection + logits — GLOBALLY LINEAR read order.
// R16 falsified the in-flight model (32 waves, 128KB/CU outstanding, still
// 2.7 TB/s). Last discriminator: the 6.4 TB/s shapes sweep memory linearly
// across the grid; all consumers scatter. This kernel makes the consumer
// linear: wg = (j, iblk); wave w -> i = iblk*8+w; loop over b-tiles so each
// wave streams its contiguous 32KB rel[j][i] block sequentially, and
// consecutive wgids cover consecutive 256KB -> whole-grid linear sweep.
// Both q and k folded into MFMA via identity k-steps (qpb page from global,
// kpb[j] page staged in LDS) -> zero scalar vmem in the loop besides the
// rel stream + 2 qpb loads. Epilogue = acc_a * acc_b (pure registers).
// Stores: direct per-iteration, 64x4B contiguous (256B/instr), youngest in
// vmcnt order (nothing waits on them). (512,4): 32 waves/CU, VGPR cap 64
// (R9-equivalent body measured 52 with MORE live state). LDS 36.9KB.
// ---------------------------------------------------------------------------
__global__ __launch_bounds__(512, 4) void k_logits_mfma(
    const float* __restrict__ rel, const ushort* __restrict__ wBf,
    const ushort* __restrict__ kpbF, const ushort* __restrict__ qpbF,
    float* __restrict__ logits)
{
    __shared__ char Bs[20480];       // 20 B-frags (16 W + 4 I), 1 KB each
    __shared__ char Ks[16384];       // kpb[j] page (wg-uniform)

    const int tid = threadIdx.x;
    const int w = tid >> 6, l = tid & 63;
    const int c = l & 15, rq = l >> 4;
    const int j = blockIdx.x >> 3;
    const int iblk = blockIdx.x & 7;
    const int i = iblk * 8 + w;

    // stage Bs (1280 float4) with 512 thr
    #pragma unroll
    for (int li = 0; li < 3; ++li) {
        int idx = li * 512 + tid;
        if (idx < 1280)
            reinterpret_cast<float4*>(Bs)[idx] =
                reinterpret_cast<const float4*>(wBf)[idx];
    }
    // stage Ks = kpb[j] (1024 float4)
    {
        const float4* kp4 = reinterpret_cast<const float4*>(kpbF + (size_t)j * 8192);
        reinterpret_cast<float4*>(Ks)[tid] = kp4[tid];
        reinterpret_cast<float4*>(Ks)[512 + tid] = kp4[512 + tid];
    }
    __syncthreads();

    const float* relbase = rel + ((size_t)j * S_ + i) * (size_t)(B_ * E_);
    const int laneoff = c * E_ + rq * 8;          // within a 4KB b-tile block
    const ushort* qpage = qpbF + (size_t)i * 8192;
    const int qfo = l * 8;

    float4 x0, x1, x2, x3;
    {
        const float* ab = relbase + laneoff;      // bt = 0
        x0 = *(const float4*)(ab);
        x1 = *(const float4*)(ab + 4);
        x2 = *(const float4*)(ab + 32);
        x3 = *(const float4*)(ab + 36);
    }
    bf16x8 qf0c = *(const bf16x8*)(qpage + qfo);
    bf16x8 qf1c = *(const bf16x8*)(qpage + 4096 + qfo);
    bf16x8 qf0n = qf0c, qf1n = qf1c;

    float* lbase = logits + ((size_t)i * S_ + j) * (size_t)(B_ * H_);
    const int soff = rq * 16 + (c & 3) * 4 + (c >> 2);

    #pragma unroll 1
    for (int bt = 0; bt < 8; ++bt) {
        // cvt this bt's A (drains LOADA(bt) + qf(bt), both issued last iter)
        bf16x8 af0, af1;
        {
            bf16x8 a;
            a[0] = f2b(x0.x); a[1] = f2b(x0.y); a[2] = f2b(x0.z); a[3] = f2b(x0.w);
            a[4] = f2b(x1.x); a[5] = f2b(x1.y); a[6] = f2b(x1.z); a[7] = f2b(x1.w);
            af0 = a;
            a[0] = f2b(x2.x); a[1] = f2b(x2.y); a[2] = f2b(x2.z); a[3] = f2b(x2.w);
            a[4] = f2b(x3.x); a[5] = f2b(x3.y); a[6] = f2b(x3.z); a[7] = f2b(x3.w);
            af1 = a;
        }

        // prefetch next b-tile: sequential 4KB advance (linear stream)
        if (bt < 7) {
            const float* ab = relbase + (bt + 1) * 1024 + laneoff;
            x0 = *(const float4*)(ab);
            x1 = *(const float4*)(ab + 4);
            x2 = *(const float4*)(ab + 32);
            x3 = *(const float4*)(ab + 36);
            qf0n = *(const bf16x8*)(qpage + (bt + 1) * 512 + qfo);
            qf1n = *(const bf16x8*)(qpage + 4096 + (bt + 1) * 512 + qfo);
        }

        // kpb frags for this bt from LDS (lgkm domain, no vmcnt interference)
        bf16x8 kf0 = *(const bf16x8*)(Ks + bt * 1024 + l * 16);
        bf16x8 kf1 = *(const bf16x8*)(Ks + 8192 + bt * 1024 + l * 16);

        // opaque offset: stops LICM from hoisting the B-frag LDS reads
        int bs0 = 0;
        asm volatile("" : "+v"(bs0));
        const char* bsp = Bs + bs0;

        f32x4 acc[8];
        #pragma unroll
        for (int ot = 0; ot < 8; ++ot) acc[ot] = (f32x4){0.f, 0.f, 0.f, 0.f};
        #pragma unroll
        for (int ot = 0; ot < 4; ++ot) {   // pa' = W_a.rel + (q+ba) via I-step
            acc[ot] = __builtin_amdgcn_mfma_f32_16x16x32_bf16(
                af0, *(const bf16x8*)(bsp + (ot * 2 + 0) * 1024 + l * 16), acc[ot], 0, 0, 0);
            acc[ot] = __builtin_amdgcn_mfma_f32_16x16x32_bf16(
                af1, *(const bf16x8*)(bsp + (ot * 2 + 1) * 1024 + l * 16), acc[ot], 0, 0, 0);
            acc[ot] = __builtin_amdgcn_mfma_f32_16x16x32_bf16(
                (ot < 2 ? qf0c : qf1c),
                *(const bf16x8*)(bsp + (16 + ot) * 1024 + l * 16), acc[ot], 0, 0, 0);
        }
        #pragma unroll
        for (int ot = 0; ot < 4; ++ot) {   // pb' = W_b.rel + (k+bb) via I-step
            acc[4 + ot] = __builtin_amdgcn_mfma_f32_16x16x32_bf16(
                af0, *(const bf16x8*)(bsp + (8 + ot * 2 + 0) * 1024 + l * 16), acc[4 + ot], 0, 0, 0);
            acc[4 + ot] = __builtin_amdgcn_mfma_f32_16x16x32_bf16(
                af1, *(const bf16x8*)(bsp + (8 + ot * 2 + 1) * 1024 + l * 16), acc[4 + ot], 0, 0, 0);
            acc[4 + ot] = __builtin_amdgcn_mfma_f32_16x16x32_bf16(
                (ot < 2 ? kf0 : kf1),
                *(const bf16x8*)(bsp + (16 + ot) * 1024 + l * 16), acc[4 + ot], 0, 0, 0);
        }

        // epilogue: v = pa' * pb'; butterfly reduce-scatter over c-lanes
        float v[16];
        #pragma unroll
        for (int h = 0; h < 4; ++h)
            #pragma unroll
            for (int r = 0; r < 4; ++r)
                v[h * 4 + r] = acc[h][r] * acc[4 + h][r];
        #pragma unroll
        for (int k = 0; k < 8; ++k) {
            float x = (c & 1) ? v[2 * k + 1] : v[2 * k];
            float y = (c & 1) ? v[2 * k] : v[2 * k + 1];
            v[k] = x + __shfl_xor(y, 1);
        }
        #pragma unroll
        for (int k = 0; k < 4; ++k) {
            float x = (c & 2) ? v[2 * k + 1] : v[2 * k];
            float y = (c & 2) ? v[2 * k] : v[2 * k + 1];
            v[k] = x + __shfl_xor(y, 2);
        }
        #pragma unroll
        for (int k = 0; k < 2; ++k) {
            float x = (c & 4) ? v[2 * k + 1] : v[2 * k];
            float y = (c & 4) ? v[2 * k] : v[2 * k + 1];
            v[k] = x + __shfl_xor(y, 4);
        }
        float outv;
        {
            float x = (c & 8) ? v[1] : v[0];
            float y = (c & 8) ? v[0] : v[1];
            outv = (x + __shfl_xor(y, 8)) * 0.0625f;
        }

        // coalesced store: 64 lanes x 4B contiguous (b = bt*16+rq*4+(c&3), h = c>>2)
        lbase[bt * 64 + soff] = outv;

        qf0c = qf0n; qf1c = qf1n;
    }
}

// ---------------------------------------------------------------------------
// K2b: softmax over j + PV + out-projection. logits layout [i][j][b][h]
// (R8's version — slab load + [64][20] LDS transpose, passed in R8).
// ---------------------------------------------------------------------------
__global__ __launch_bounds__(256) void k_attn(
    const float* __restrict__ logits, const float* __restrict__ qkv,
    const float* __restrict__ Wout, const float* __restrict__ bout,
    float* __restrict__ out)
{
    __shared__ float trans[64][20];
    __shared__ float wsm[4][H_][S_];
    __shared__ float ap[4][68];
    const int tid = threadIdx.x;
    const int i = blockIdx.x >> 5;
    const int bq = blockIdx.x & 31;
    const int w = tid >> 6, l = tid & 63;
    const int b = bq * 4 + w;

    // load slab: thread p -> j = p>>2, quarter q = p&3 (float4 of 16-float row)
    {
        const int jj = tid >> 2, q = tid & 3;
        float4 lv = *(const float4*)(logits + ((size_t)i * S_ + jj) * (B_ * H_) + bq * 16 + q * 4);
        *reinterpret_cast<float4*>(&trans[jj][q * 4]) = lv;
    }
    __syncthreads();

    // softmax: lane (h = l>>4, sub = l&15); col = w*4 + h
    const int h = l >> 4, sub = l & 15;
    const int col = w * 4 + h;
    float v0 = trans[sub][col];
    float v1 = trans[sub + 16][col];
    float v2 = trans[sub + 32][col];
    float v3 = trans[sub + 48][col];
    float m = fmaxf(fmaxf(v0, v1), fmaxf(v2, v3));
    #pragma unroll
    for (int d = 1; d < 16; d <<= 1) m = fmaxf(m, __shfl_xor(m, d));
    float e0 = expf(v0 - m), e1 = expf(v1 - m), e2 = expf(v2 - m), e3 = expf(v3 - m);
    float ss = e0 + e1 + e2 + e3;
    #pragma unroll
    for (int d = 1; d < 16; d <<= 1) ss += __shfl_xor(ss, d);
    float inv = 1.0f / ss;
    wsm[w][h][sub] = e0 * inv;
    wsm[w][h][sub + 16] = e1 * inv;
    wsm[w][h][sub + 32] = e2 * inv;
    wsm[w][h][sub + 48] = e3 * inv;
    __syncthreads();

    const float* vbase = qkv + (size_t)2 * T_ * B_ * E_ + (size_t)b * E_;
    const float* wrow = &wsm[w][l >> 4][0];
    float acc = 0.f;
    #pragma unroll 4
    for (int j = 0; j < S_; ++j) acc += wrow[j] * vbase[(size_t)j * B_ * E_ + l];
    ap[w][l] = acc;
    __syncthreads();

    const float* wo = Wout + l * E_;
    const float* apw = ap[w];
    float oacc = bout[l];
    #pragma unroll 4
    for (int e = 0; e < E_; ++e) oacc += apw[e] * wo[e];
    out[((size_t)i * B_ + b) * E_ + l] = oacc;
}

// ---------------------------------------------------------------------------
extern "C" void kernel_launch(void* const* d_in, const int* in_sizes, int n_in,
                              void* d_out, int out_size, void* d_ws, size_t ws_size,
                              hipStream_t stream)
{
    const float* qin = (const float*)d_in[0];
    const float* kin = (const float*)d_in[1];
    const float* vin = (const float*)d_in[2];
    const float* rel = (const float*)d_in[3];
    const float* ipw = (const float*)d_in[4];
    const float* ipb = (const float*)d_in[5];
    const float* rw  = (const float*)d_in[6];
    const float* rb  = (const float*)d_in[7];
    const float* ow  = (const float*)d_in[8];
    const float* obias = (const float*)d_in[9];

    float* qkv = (float*)d_ws;                        // 3*64*128*64 fl = 6 MB
    float* logits = qkv + 3 * T_ * B_ * E_;           // [i][j][b][h]  = 8 MB
    ushort* wBf  = (ushort*)(logits + (size_t)T_ * S_ * B_ * H_); // 20 KB (+pad)
    ushort* kpbF = wBf + 16384;                       // 64 pages x 16 KB = 1 MB
    ushort* qpbF = kpbF + 524288;                     // 64 pages x 16 KB = 1 MB

    float* out = (float*)d_out;

    k_qkv<<<dim3(257), dim3(256), 0, stream>>>(qin, kin, vin, ipw, ipb, qkv,
                                               rw, rb, wBf, (unsigned int*)kpbF,
                                               (unsigned int*)qpbF);
    k_logits_mfma<<<dim3(512), dim3(512), 0, stream>>>(rel, wBf, kpbF, qpbF, logits);
    k_attn<<<dim3(2048), dim3(256), 0, stream>>>(logits, qkv, ow, obias, out);
}